// Round 1
// baseline (205.848 us; speedup 1.0000x reference)
//
#include <hip/hip_runtime.h>
#include <stdint.h>

#define BB 256
#define VV 128000
#define THREADS 512
#define WAVES (THREADS / 64)

// ---- Threefry-2x32, 20 rounds, key = (0, 42) (jax.random.key(42)) ----
__device__ __forceinline__ void threefry_0_42(uint32_t x0, uint32_t x1,
                                              uint32_t& o0, uint32_t& o1) {
    const uint32_t k0 = 0u;
    const uint32_t k1 = 42u;
    const uint32_t k2 = 0x1BD11BDAu ^ k0 ^ k1;

    x0 += k0;
    x1 += k1;

#define TF_ROUND(r)                                  \
    do {                                             \
        x0 += x1;                                    \
        x1 = (x1 << (r)) | (x1 >> (32 - (r)));       \
        x1 ^= x0;                                    \
    } while (0)

    TF_ROUND(13); TF_ROUND(15); TF_ROUND(26); TF_ROUND(6);
    x0 += k1; x1 += k2 + 1u;
    TF_ROUND(17); TF_ROUND(29); TF_ROUND(16); TF_ROUND(24);
    x0 += k2; x1 += k0 + 2u;
    TF_ROUND(13); TF_ROUND(15); TF_ROUND(26); TF_ROUND(6);
    x0 += k0; x1 += k1 + 3u;
    TF_ROUND(17); TF_ROUND(29); TF_ROUND(16); TF_ROUND(24);
    x0 += k1; x1 += k2 + 4u;
    TF_ROUND(13); TF_ROUND(15); TF_ROUND(26); TF_ROUND(6);
    x0 += k2; x1 += k0 + 5u;
#undef TF_ROUND

    o0 = x0;
    o1 = x1;
}

// order-preserving float -> uint32 map
__device__ __forceinline__ uint32_t f2o(float f) {
    uint32_t u = __float_as_uint(f);
    return (u & 0x80000000u) ? ~u : (u | 0x80000000u);
}

__global__ __launch_bounds__(THREADS) void sampler_kernel(
    const float* __restrict__ logits,
    const float* __restrict__ temps,
    int* __restrict__ out) {
    const int b = blockIdx.x;
    const float T = temps[b];
    const float* row = logits + (size_t)b * VV;
    const uint32_t ibase = (uint32_t)b * (uint32_t)VV;  // flat index base, < 2^32

    unsigned long long best = 0ull;  // (orderable(score) << 32) | ~v

    for (int v0 = threadIdx.x * 4; v0 < VV; v0 += THREADS * 4) {
        const float4 x4 = *reinterpret_cast<const float4*>(row + v0);
        float xs[4] = {x4.x, x4.y, x4.z, x4.w};

#pragma unroll
        for (int j = 0; j < 4; ++j) {
            const uint32_t v = (uint32_t)v0 + (uint32_t)j;
            // JAX partitionable threefry: bits = o0 ^ o1 of threefry(key, (0, i))
            uint32_t o0, o1;
            threefry_0_42(0u, ibase + v, o0, o1);
            const uint32_t bits = o0 ^ o1;
            // jax.random.uniform: u in [0,1): bitcast((bits>>9) | 0x3f800000) - 1
            const float u = __uint_as_float(0x3F800000u | (bits >> 9)) - 1.0f;
            // exponential = -log1p(-u); clamp_min 1e-10
            const float E = fmaxf(-log1pf(-u), 1e-10f);
            // log-domain score: x/T - log(E)  (same argmax as probs/E)
            const float s = xs[j] / T - logf(E);

            const unsigned long long p =
                ((unsigned long long)f2o(s) << 32) | (uint32_t)(~v);
            best = (p > best) ? p : best;
        }
    }

    // wave (64-lane) max reduction
#pragma unroll
    for (int off = 32; off >= 1; off >>= 1) {
        const unsigned long long o = __shfl_xor(best, off);
        best = (o > best) ? o : best;
    }

    __shared__ unsigned long long sbest[WAVES];
    const int lane = threadIdx.x & 63;
    const int wid = threadIdx.x >> 6;
    if (lane == 0) sbest[wid] = best;
    __syncthreads();

    if (threadIdx.x == 0) {
        unsigned long long r = sbest[0];
#pragma unroll
        for (int w = 1; w < WAVES; ++w) r = (sbest[w] > r) ? sbest[w] : r;
        out[b] = (int)(~(uint32_t)(r & 0xFFFFFFFFull));
    }
}

extern "C" void kernel_launch(void* const* d_in, const int* in_sizes, int n_in,
                              void* d_out, int out_size, void* d_ws, size_t ws_size,
                              hipStream_t stream) {
    const float* logits = (const float*)d_in[0];
    const float* temps = (const float*)d_in[1];
    int* out = (int*)d_out;

    hipLaunchKernelGGL(sampler_kernel, dim3(BB), dim3(THREADS), 0, stream,
                       logits, temps, out);
}

// Round 2
// 95.655 us; speedup vs baseline: 2.1520x; 2.1520x over previous
//
#include <hip/hip_runtime.h>
#include <stdint.h>
#include <math.h>

#define BB 256
#define VV 128000
#define THREADS 1024
#define WAVES (THREADS / 64)

// ---- Threefry-2x32, 20 rounds, key = (0, 42) (jax.random.key(42)) ----
__device__ __forceinline__ void threefry_0_42(uint32_t x0, uint32_t x1,
                                              uint32_t& o0, uint32_t& o1) {
    const uint32_t k0 = 0u;
    const uint32_t k1 = 42u;
    const uint32_t k2 = 0x1BD11BDAu ^ k0 ^ k1;

    x0 += k0;
    x1 += k1;

#define TF_ROUND(r)                                  \
    do {                                             \
        x0 += x1;                                    \
        x1 = (x1 << (r)) | (x1 >> (32 - (r)));       \
        x1 ^= x0;                                    \
    } while (0)

    TF_ROUND(13); TF_ROUND(15); TF_ROUND(26); TF_ROUND(6);
    x0 += k1; x1 += k2 + 1u;
    TF_ROUND(17); TF_ROUND(29); TF_ROUND(16); TF_ROUND(24);
    x0 += k2; x1 += k0 + 2u;
    TF_ROUND(13); TF_ROUND(15); TF_ROUND(26); TF_ROUND(6);
    x0 += k0; x1 += k1 + 3u;
    TF_ROUND(17); TF_ROUND(29); TF_ROUND(16); TF_ROUND(24);
    x0 += k1; x1 += k2 + 4u;
    TF_ROUND(13); TF_ROUND(15); TF_ROUND(26); TF_ROUND(6);
    x0 += k2; x1 += k0 + 5u;
#undef TF_ROUND

    o0 = x0;
    o1 = x1;
}

// order-preserving float -> uint32 map (for the final reduction only)
__device__ __forceinline__ uint32_t f2o(float f) {
    uint32_t u = __float_as_uint(f);
    return (u & 0x80000000u) ? ~u : (u | 0x80000000u);
}

// ln(E) where E = max(-log1p(-u), 1e-10), computed with 2x v_log_f32.
// u = (bits>>9) * 2^-23 exactly; m = 1-u is exactly representable.
__device__ __forceinline__ float log_exp_noise(uint32_t bits) {
    const float uf = __uint_as_float(0x3F800000u | (bits >> 9));  // 1+u in [1,2)
    const float u = uf - 1.0f;   // exact
    const float m = 2.0f - uf;   // exact 1-u
    // main path: E = -ln(m) = ln2 * (-log2(m));  lnE = ln(ln2) + ln2*log2(P)
    const float lg_m = __builtin_amdgcn_logf(m);  // v_log_f32: log2(m) <= 0
    // small-u path: E = u + u^2/2 + ... + u^5/5 (rel err ~6e-8 at u=2^-4)
    const float es =
        u * fmaf(u, fmaf(u, fmaf(u, fmaf(u, 0.2f, 0.25f), 0.33333333333f), 0.5f), 1.0f);
    const bool small = (u < 0.0625f);
    float P = small ? es : -lg_m;
    const float csel = small ? 0.0f : -0.36651292058166432701f;  // ln(ln2)
    // clamp: only u==0 (P==0, series path) can be below; matches ref's 1e-10 clamp
    P = fmaxf(P, 1e-10f);
    return fmaf(0.69314718055994530942f, __builtin_amdgcn_logf(P), csel);  // ln(E)
}

__global__ __launch_bounds__(THREADS, 4) void sampler_kernel(
    const float* __restrict__ logits,
    const float* __restrict__ temps,
    int* __restrict__ out) {
    const int b = blockIdx.x;
    const float invT = 1.0f / temps[b];
    const float* row = logits + (size_t)b * VV;
    const uint32_t ibase = (uint32_t)b * (uint32_t)VV;

    float best_s = -INFINITY;
    uint32_t best_v = 0u;

    const int tid = threadIdx.x;

#pragma unroll 1
    for (int base = 0; base < VV; base += THREADS * 8) {
        const int i1 = base + tid * 4;
        const int i2 = base + THREADS * 4 + tid * 4;

        if (i1 < VV) {
            const float4 x4 = *reinterpret_cast<const float4*>(row + i1);
            const float xs[4] = {x4.x, x4.y, x4.z, x4.w};
#pragma unroll
            for (int j = 0; j < 4; ++j) {
                const uint32_t v = (uint32_t)i1 + (uint32_t)j;
                uint32_t o0, o1;
                threefry_0_42(0u, ibase + v, o0, o1);
                const float lnE = log_exp_noise(o0 ^ o1);
                const float s = fmaf(xs[j], invT, -lnE);
                if (s > best_s) { best_s = s; best_v = v; }
            }
        }
        if (i2 < VV) {
            const float4 x4 = *reinterpret_cast<const float4*>(row + i2);
            const float xs[4] = {x4.x, x4.y, x4.z, x4.w};
#pragma unroll
            for (int j = 0; j < 4; ++j) {
                const uint32_t v = (uint32_t)i2 + (uint32_t)j;
                uint32_t o0, o1;
                threefry_0_42(0u, ibase + v, o0, o1);
                const float lnE = log_exp_noise(o0 ^ o1);
                const float s = fmaf(xs[j], invT, -lnE);
                if (s > best_s) { best_s = s; best_v = v; }
            }
        }
    }

    // pack (orderable(score) << 32) | ~v  -> max-reduce; ties pick smallest v
    unsigned long long best =
        ((unsigned long long)f2o(best_s) << 32) | (uint32_t)(~best_v);

    // wave (64-lane) max reduction
#pragma unroll
    for (int off = 32; off >= 1; off >>= 1) {
        const unsigned long long o = __shfl_xor(best, off);
        best = (o > best) ? o : best;
    }

    __shared__ unsigned long long sbest[WAVES];
    const int lane = tid & 63;
    const int wid = tid >> 6;
    if (lane == 0) sbest[wid] = best;
    __syncthreads();

    if (tid == 0) {
        unsigned long long r = sbest[0];
#pragma unroll
        for (int w = 1; w < WAVES; ++w) r = (sbest[w] > r) ? sbest[w] : r;
        out[b] = (int)(~(uint32_t)(r & 0xFFFFFFFFull));
    }
}

extern "C" void kernel_launch(void* const* d_in, const int* in_sizes, int n_in,
                              void* d_out, int out_size, void* d_ws, size_t ws_size,
                              hipStream_t stream) {
    const float* logits = (const float*)d_in[0];
    const float* temps = (const float*)d_in[1];
    int* out = (int*)d_out;

    hipLaunchKernelGGL(sampler_kernel, dim3(BB), dim3(THREADS), 0, stream,
                       logits, temps, out);
}

// Round 3
// 93.521 us; speedup vs baseline: 2.2011x; 1.0228x over previous
//
#include <hip/hip_runtime.h>
#include <stdint.h>
#include <math.h>

#define BB 256
#define ROW 128000
#define SPLIT 4
#define CHUNK (ROW / SPLIT)      // 32000
#define THREADS 512
#define WAVES (THREADS / 64)
#define GRID (BB * SPLIT)        // 1024 blocks -> 4 per CU, 32 waves/CU

__device__ __forceinline__ uint32_t rotl32(uint32_t x, int r) {
    return (x << r) | (x >> (32 - r));
}

// ---- Threefry-2x32, key=(0,42), 4 independent counters interleaved ----
// counters are (hi=0, lo=c+j), j=0..3; output bits[j] = o0^o1 (JAX
// partitionable threefry). Bit-exact vs jax.random.exponential(key(42)).
#define TF_K2 0x1BD11BF0u  // 0x1BD11BDA ^ 0 ^ 42

__device__ __forceinline__ void threefry4_xor(uint32_t c, uint32_t bits[4]) {
    uint32_t x0[4], x1[4];
#pragma unroll
    for (int j = 0; j < 4; ++j) {
        x0[j] = 0u;                       // ctr_hi + k0
        x1[j] = c + (uint32_t)j + 42u;    // ctr_lo + k1
    }

#define ROUND4(r)                                     \
    do {                                              \
        _Pragma("unroll")                             \
        for (int j = 0; j < 4; ++j) {                 \
            x0[j] += x1[j];                           \
            x1[j] = rotl32(x1[j], (r));               \
            x1[j] ^= x0[j];                           \
        }                                             \
    } while (0)
#define INJ4(a, b)                                    \
    do {                                              \
        _Pragma("unroll")                             \
        for (int j = 0; j < 4; ++j) {                 \
            x0[j] += (a);                             \
            x1[j] += (b);                             \
        }                                             \
    } while (0)

    ROUND4(13); ROUND4(15); ROUND4(26); ROUND4(6);
    INJ4(42u, TF_K2 + 1u);
    ROUND4(17); ROUND4(29); ROUND4(16); ROUND4(24);
    INJ4(TF_K2, 2u);
    ROUND4(13); ROUND4(15); ROUND4(26); ROUND4(6);
    INJ4(0u, 45u);
    ROUND4(17); ROUND4(29); ROUND4(16); ROUND4(24);
    INJ4(42u, TF_K2 + 4u);
    ROUND4(13); ROUND4(15); ROUND4(26); ROUND4(6);
    INJ4(TF_K2, 5u);

#undef ROUND4
#undef INJ4

#pragma unroll
    for (int j = 0; j < 4; ++j) bits[j] = x0[j] ^ x1[j];
}

// order-preserving float -> uint32 map (final reduction only)
__device__ __forceinline__ uint32_t f2o(float f) {
    uint32_t u = __float_as_uint(f);
    return (u & 0x80000000u) ? ~u : (u | 0x80000000u);
}

// ln(E) where E = max(-log1p(-u), 1e-10); u = (bits>>9)*2^-23 exactly.
__device__ __forceinline__ float log_exp_noise(uint32_t bits) {
    const float uf = __uint_as_float(0x3F800000u | (bits >> 9));  // 1+u in [1,2)
    const float u = uf - 1.0f;   // exact
    const float m = 2.0f - uf;   // exact 1-u
    const float lg_m = __builtin_amdgcn_logf(m);  // v_log_f32: log2(1-u)
    // small-u series for E = -log1p(-u), rel err ~6e-8 at u<=2^-4
    const float es =
        u * fmaf(u, fmaf(u, fmaf(u, fmaf(u, 0.2f, 0.25f), 0.33333333333f), 0.5f), 1.0f);
    const bool small = (u < 0.0625f);
    float P = small ? es : -lg_m;
    const float csel = small ? 0.0f : -0.36651292058166432701f;  // ln(ln2)
    P = fmaxf(P, 1e-10f);  // only u==0 hits this (matches ref clamp)
    return fmaf(0.69314718055994530942f, __builtin_amdgcn_logf(P), csel);
}

__global__ __launch_bounds__(THREADS, 8) void sampler_kernel(
    const float* __restrict__ logits,
    const float* __restrict__ temps,
    unsigned long long* __restrict__ ws) {
    const int g = blockIdx.x;
    const int b = g >> 2;        // row
    const int q = g & 3;         // quarter
    const float invT = 1.0f / temps[b];
    const float* rowp = logits + (size_t)b * ROW + (size_t)q * CHUNK;
    const uint32_t cbase = (uint32_t)b * (uint32_t)ROW + (uint32_t)q * CHUNK;

    float best_s = -INFINITY;
    uint32_t best_v = 0u;
    const int tid = threadIdx.x;

#pragma unroll 1
    for (int t = 0; t < (CHUNK + THREADS * 4 - 1) / (THREADS * 4); ++t) {
        const int vl = t * THREADS * 4 + tid * 4;
        if (vl < CHUNK) {
            const float4 x4 = *reinterpret_cast<const float4*>(rowp + vl);
            const float xs[4] = {x4.x, x4.y, x4.z, x4.w};

            uint32_t bits[4];
            threefry4_xor(cbase + (uint32_t)vl, bits);

            float s[4];
#pragma unroll
            for (int j = 0; j < 4; ++j)
                s[j] = fmaf(xs[j], invT, -log_exp_noise(bits[j]));

#pragma unroll
            for (int j = 0; j < 4; ++j) {
                const uint32_t v = (uint32_t)(q * CHUNK + vl) + (uint32_t)j;
                if (s[j] > best_s) { best_s = s[j]; best_v = v; }
            }
        }
    }

    // pack (orderable(score) << 32) | ~v ; max-reduce; ties -> smallest v
    unsigned long long best =
        ((unsigned long long)f2o(best_s) << 32) | (uint32_t)(~best_v);

#pragma unroll
    for (int off = 32; off >= 1; off >>= 1) {
        const unsigned long long o = __shfl_xor(best, off);
        best = (o > best) ? o : best;
    }

    __shared__ unsigned long long sbest[WAVES];
    const int lane = tid & 63;
    const int wid = tid >> 6;
    if (lane == 0) sbest[wid] = best;
    __syncthreads();

    if (tid == 0) {
        unsigned long long r = sbest[0];
#pragma unroll
        for (int w = 1; w < WAVES; ++w) r = (sbest[w] > r) ? sbest[w] : r;
        ws[g] = r;
    }
}

__global__ __launch_bounds__(BB) void combine_kernel(
    const unsigned long long* __restrict__ ws, int* __restrict__ out) {
    const int b = threadIdx.x;
    const unsigned long long* p = ws + b * SPLIT;
    unsigned long long r = p[0];
#pragma unroll
    for (int w = 1; w < SPLIT; ++w) r = (p[w] > r) ? p[w] : r;
    out[b] = (int)(~(uint32_t)(r & 0xFFFFFFFFull));
}

extern "C" void kernel_launch(void* const* d_in, const int* in_sizes, int n_in,
                              void* d_out, int out_size, void* d_ws, size_t ws_size,
                              hipStream_t stream) {
    const float* logits = (const float*)d_in[0];
    const float* temps = (const float*)d_in[1];
    int* out = (int*)d_out;
    unsigned long long* ws = (unsigned long long*)d_ws;

    hipLaunchKernelGGL(sampler_kernel, dim3(GRID), dim3(THREADS), 0, stream,
                       logits, temps, ws);
    hipLaunchKernelGGL(combine_kernel, dim3(1), dim3(BB), 0, stream, ws, out);
}